// Round 2
// baseline (1856.491 us; speedup 1.0000x reference)
//
#include <hip/hip_runtime.h>
#include <hip/hip_bf16.h>
#include <math.h>

constexpr int NE  = 16;   // experts
constexpr int NG  = 4;    // groups
constexpr int TPB = 64;   // tokens per block (= lanes, 1 wave/block)
constexpr int DC  = 32;   // dims per chunk
constexpr int LSTRIDE = 36; // padded LDS row stride in floats

__global__ __launch_bounds__(64)
void router_kernel(const float* __restrict__ x,
                   const float* __restrict__ w1w,
                   const float* __restrict__ w1b,
                   const float* __restrict__ rbias,
                   float* __restrict__ dout,
                   int n_tokens, int dim)
{
    const int lane = threadIdx.x;           // 0..63, one token per lane
    const long t0 = (long)blockIdx.x * TPB;
    const int nch = dim / DC;               // 128 chunks

    __shared__ float xs[TPB][LSTRIDE];

    double acc[NE];
#pragma unroll
    for (int e = 0; e < NE; ++e) acc[e] = 0.0;

    // staging mapping: 8 lanes per token row, 128B contiguous per 8-lane group
    const int srow = lane >> 3;             // 0..7
    const int scol = (lane & 7) << 2;       // 0,4,...,28
    const float* xblk = x + t0 * (long)dim;

    // prefetch chunk 0 into registers
    float4 st[8];
#pragma unroll
    for (int p = 0; p < 8; ++p)
        st[p] = *(const float4*)(xblk + (long)(p * 8 + srow) * dim + scol);

    for (int c = 0; c < nch; ++c) {
        // write staged chunk into LDS (single wave per block; DS ops in-order)
#pragma unroll
        for (int p = 0; p < 8; ++p)
            *(float4*)&xs[p * 8 + srow][scol] = st[p];

        // issue next chunk's global loads (overlap with compute below)
        if (c + 1 < nch) {
            const float* xb = xblk + (c + 1) * DC;
#pragma unroll
            for (int p = 0; p < 8; ++p)
                st[p] = *(const float4*)(xb + (long)(p * 8 + srow) * dim + scol);
        }

        // compute: fp64 FMA accumulation (ranking-exact vs golden reference)
        const float* wch = w1w + c * DC;
#pragma unroll
        for (int d4 = 0; d4 < DC / 4; ++d4) {
            float4 xv = *(const float4*)&xs[lane][d4 * 4];
            double x0 = (double)xv.x, x1 = (double)xv.y;
            double x2 = (double)xv.z, x3 = (double)xv.w;
#pragma unroll
            for (int e = 0; e < NE; ++e) {
                const float* wr = wch + e * dim + d4 * 4;  // uniform -> scalar loads
                acc[e] = fma(x0, (double)wr[0], acc[e]);
                acc[e] = fma(x1, (double)wr[1], acc[e]);
                acc[e] = fma(x2, (double)wr[2], acc[e]);
                acc[e] = fma(x3, (double)wr[3], acc[e]);
            }
        }
    }

    // ---- epilogue in fp64: softmax + bias + group-limited top-2 ----
    double logit[NE];
    double m = -INFINITY;
#pragma unroll
    for (int e = 0; e < NE; ++e) {
        logit[e] = acc[e] + (double)w1b[e];
        m = fmax(m, logit[e]);
    }
    double s = 0.0;
    double p[NE];
#pragma unroll
    for (int e = 0; e < NE; ++e) { p[e] = exp(logit[e] - m); s += p[e]; }
    double inv = 1.0 / s;
    double sc[NE];
#pragma unroll
    for (int e = 0; e < NE; ++e) sc[e] = p[e] * inv + (double)rbias[e];

    // group maxes
    double gm[NG];
#pragma unroll
    for (int g = 0; g < NG; ++g) {
        double a = fmax(sc[g * 4 + 0], sc[g * 4 + 1]);
        double b = fmax(sc[g * 4 + 2], sc[g * 4 + 3]);
        gm[g] = fmax(a, b);
    }
    // top-2 groups (strict > ascending scan == lowest-index tie-break)
    int g1 = 0;
#pragma unroll
    for (int g = 1; g < NG; ++g) if (gm[g] > gm[g1]) g1 = g;
    int g2 = (g1 == 0) ? 1 : 0;
#pragma unroll
    for (int g = 0; g < NG; ++g) if (g != g1 && gm[g] > gm[g2]) g2 = g;

    // top-2 experts within kept groups (stable: lowest index on ties)
    double v1 = -INFINITY; int i1 = 0;
#pragma unroll
    for (int e = 0; e < NE; ++e) {
        int g = e >> 2;
        bool keep = (g == g1) || (g == g2);
        if (keep && sc[e] > v1) { v1 = sc[e]; i1 = e; }
    }
    double v2 = -INFINITY; int i2 = 0;
#pragma unroll
    for (int e = 0; e < NE; ++e) {
        int g = e >> 2;
        bool keep = ((g == g1) || (g == g2)) && (e != i1);
        if (keep && sc[e] > v2) { v2 = sc[e]; i2 = e; }
    }

    // outputs: values [N,2] fp32, then indices [N,2] written as numeric floats
    long t = t0 + lane;
    float2 vv; vv.x = (float)v1; vv.y = (float)v2;
    *(float2*)(dout + t * 2) = vv;
    float2 iv; iv.x = (float)i1; iv.y = (float)i2;
    *(float2*)(dout + (long)n_tokens * 2 + t * 2) = iv;
}

extern "C" void kernel_launch(void* const* d_in, const int* in_sizes, int n_in,
                              void* d_out, int out_size, void* d_ws, size_t ws_size,
                              hipStream_t stream)
{
    const float* x   = (const float*)d_in[0];
    const float* w1w = (const float*)d_in[1];
    const float* w1b = (const float*)d_in[2];
    const float* rb  = (const float*)d_in[3];
    float* out = (float*)d_out;

    const int ne       = in_sizes[2];            // 16
    const int dim      = in_sizes[1] / ne;       // 4096
    const int n_tokens = in_sizes[0] / dim;      // 65536

    dim3 grid(n_tokens / TPB), block(TPB);
    hipLaunchKernelGGL(router_kernel, grid, block, 0, stream,
                       x, w1w, w1b, rb, out, n_tokens, dim);
}